// Round 8
// baseline (141.744 us; speedup 1.0000x reference)
//
#include <hip/hip_runtime.h>

#define N_NODES 8192
#define IN_F    1024
#define OUT_F   512
#define N_EDGES 262144
#define STRIDE  96                // fixed adjacency row stride; P(deg>=96) ~ 1e-18

// ---------------- workspace layout (bytes) ----------------
#define HID_OFF     0u            // 8192*512*2  = 8,388,608  (bf16 H)
#define WB_OFF      8388608u      // 512*1024*2  = 1,048,576  (bf16 W)
#define DEG_OFF     9437184u      // 8192*4 = 32,768
#define COL_OFF     9469952u      // 8192*96*4 = 3,145,728 -> ends 12,615,680
#define MAX_DEG     STRIDE

typedef short  bf16x8 __attribute__((ext_vector_type(8)));
typedef float  f32x4  __attribute__((ext_vector_type(4)));

__device__ __forceinline__ unsigned f2bf(float f) {
    unsigned u = __float_as_uint(f);
    u += 0x7fffu + ((u >> 16) & 1u);   // round-to-nearest-even
    return u >> 16;
}

__device__ __forceinline__ float bflo(unsigned u) { return __uint_as_float(u << 16); }
__device__ __forceinline__ float bfhi(unsigned u) { return __uint_as_float(u & 0xffff0000u); }

__device__ __forceinline__ void ld_lds16(const void* g, void* l) {
    __builtin_amdgcn_global_load_lds(
        (const __attribute__((address_space(1))) void*)g,
        (__attribute__((address_space(3))) void*)l, 16, 0, 0);
}

// --- prep: W fp32 -> bf16 (1 MB) + zero deg. 65536 threads, ~1.5 us ---
#define NW8 (OUT_F * IN_F / 8)            // 65,536 chunks of 8
__global__ __launch_bounds__(256) void prep(const float* __restrict__ w,
                                            unsigned short* __restrict__ wb,
                                            int* __restrict__ deg) {
    int i = blockIdx.x * blockDim.x + threadIdx.x;
    if (i < N_NODES) deg[i] = 0;
    const f32x4* p = (const f32x4*)w + (size_t)i * 2;
    f32x4 v0 = __builtin_nontemporal_load(p);      // W fp32 read exactly once
    f32x4 v1 = __builtin_nontemporal_load(p + 1);
    uint4 o;
    o.x = f2bf(v0.x) | (f2bf(v0.y) << 16);
    o.y = f2bf(v0.z) | (f2bf(v0.w) << 16);
    o.z = f2bf(v1.x) | (f2bf(v1.y) << 16);
    o.w = f2bf(v1.z) | (f2bf(v1.w) << 16);
    *((uint4*)wb + i) = o;
}

// ------- fused: MFMA GEMM (blocks 0..1023) + edge scatter (1024..2047) -----
// GEMM: 64x64 tile, BK=64 (16 iters), 4 waves (2x2), each wave 2x2 of 16x16x32.
// A-path: X fp32 loaded global->reg, converted to bf16 in-reg, ds_write_b128
//   into the XOR-swizzled LDS layout (no cvt pre-pass / no Xb round trip).
//   bid = col_tile*128 + row_tile => all 8 col-tiles of a row-tile share an XCD
//   (bid mod 8 == row_tile mod 8) so the 8x logical X re-read is L2-served.
// B-path: pre-converted bf16 W via global_load_lds (lane-pinned, swizzled fetch).
// LDS chunk (row, kc) lives at slot kc^(row&7) -> conflict-free fragment reads.
__global__ __launch_bounds__(256, 6) void gemm_scatter(const float* __restrict__ X,
                                                       const unsigned short* __restrict__ Wb,
                                                       const float* __restrict__ bias,
                                                       unsigned short* __restrict__ H,
                                                       const int* __restrict__ src,
                                                       const int* __restrict__ dst,
                                                       int* __restrict__ deg,
                                                       int* __restrict__ col) {
    __shared__ unsigned short As[64 * 64];   // 8 KB
    __shared__ unsigned short Bs[64 * 64];   // 8 KB

    const int bid = blockIdx.x;
    const int tid = threadIdx.x;

    if (bid >= 1024) {                       // ---- scatter part ----
        int e = (bid - 1024) * 256 + tid;    // 1024*256 == N_EDGES exactly
        int s = src[e];
        int slot = atomicAdd(&deg[s], 1);
        if (slot < STRIDE) col[s * STRIDE + slot] = dst[e];
        return;
    }

    // ---- GEMM part ----
    const int lane = tid & 63;
    const int wave = tid >> 6;
    const int row0 = (bid & 127) * 64;       // 128 row-tiles
    const int col0 = (bid >> 7) * 64;        // 8 col-tiles
    const int wm   = (wave & 1) * 32;
    const int wn   = (wave >> 1) * 32;
    const int fm   = lane & 15;
    const int fm7  = fm & 7;
    const int q    = lane >> 4;              // k-quad within the 32-k MFMA window

    f32x4 acc[2][2];
#pragma unroll
    for (int i = 0; i < 2; ++i)
#pragma unroll
        for (int j = 0; j < 2; ++j) acc[i][j] = (f32x4)0.f;

    // A staging: thread -> (row ar, k-quarter ak4 of 16 floats) = 4 float4 loads,
    // packed into two 16B LDS chunks kc = ak4*2, ak4*2+1 at swizzled slots.
    const int ar   = tid >> 2;                       // 0..63
    const int ak4  = tid & 3;                        // 0..3
    const int ar7  = ar & 7;
    unsigned short* As_w0 = As + ar * 64 + ((ak4 * 2)     ^ ar7) * 8;
    unsigned short* As_w1 = As + ar * 64 + ((ak4 * 2 + 1) ^ ar7) * 8;
    const float* xrow = &X[(size_t)(row0 + ar) * IN_F + ak4 * 16];

    // B staging: slot tid -> (row tid>>3, swizzled chunk), slot tid+256 -> row+32
    const int br = tid >> 3;                         // 0..31
    const int bk = ((tid & 7) ^ (br & 7)) * 8;       // swizzled k elem-offset

    for (int k0 = 0; k0 < IN_F; k0 += 64) {
        const f32x4* px = (const f32x4*)(xrow + k0);
        f32x4 v0 = px[0], v1 = px[1], v2 = px[2], v3 = px[3];
        ld_lds16(Wb + (size_t)(col0 + br) * IN_F + k0 + bk,      Bs + tid * 8);
        ld_lds16(Wb + (size_t)(col0 + br + 32) * IN_F + k0 + bk, Bs + (tid + 256) * 8);
        uint4 pa, pb;
        pa.x = f2bf(v0.x) | (f2bf(v0.y) << 16);
        pa.y = f2bf(v0.z) | (f2bf(v0.w) << 16);
        pa.z = f2bf(v1.x) | (f2bf(v1.y) << 16);
        pa.w = f2bf(v1.z) | (f2bf(v1.w) << 16);
        pb.x = f2bf(v2.x) | (f2bf(v2.y) << 16);
        pb.y = f2bf(v2.z) | (f2bf(v2.w) << 16);
        pb.z = f2bf(v3.x) | (f2bf(v3.y) << 16);
        pb.w = f2bf(v3.z) | (f2bf(v3.w) << 16);
        *(uint4*)As_w0 = pa;
        *(uint4*)As_w1 = pb;
        __syncthreads();

#pragma unroll
        for (int s = 0; s < 2; ++s) {        // two 32-k MFMA windows per BK=64 tile
            const int kq = s * 4 + q;
            bf16x8 a[2], b[2];
#pragma unroll
            for (int mi = 0; mi < 2; ++mi)
                a[mi] = *(const bf16x8*)&As[(((wm + mi * 16 + fm) << 3) + (kq ^ fm7)) << 3];
#pragma unroll
            for (int ni = 0; ni < 2; ++ni)
                b[ni] = *(const bf16x8*)&Bs[(((wn + ni * 16 + fm) << 3) + (kq ^ fm7)) << 3];
#pragma unroll
            for (int mi = 0; mi < 2; ++mi)
#pragma unroll
                for (int ni = 0; ni < 2; ++ni)
                    acc[mi][ni] = __builtin_amdgcn_mfma_f32_16x16x32_bf16(
                        a[mi], b[ni], acc[mi][ni], 0, 0, 0);
        }
        __syncthreads();
    }

    const int cm = (lane >> 4) * 4;   // C/D: col = lane&15, row = (lane>>4)*4 + reg
#pragma unroll
    for (int ni = 0; ni < 2; ++ni) {
        const int c = col0 + wn + ni * 16 + fm;
        const float bv = bias[c];
#pragma unroll
        for (int mi = 0; mi < 2; ++mi) {
#pragma unroll
            for (int r = 0; r < 4; ++r) {
                const int row = row0 + wm + mi * 16 + cm + r;
                H[(size_t)row * OUT_F + c] = (unsigned short)f2bf(acc[mi][ni][r] + bv);
            }
        }
    }
}

// ---- aggregate: wave-per-node. 64 lanes x 8 feats = 512. No block barriers. ----
__global__ __launch_bounds__(256) void aggregate(const unsigned short* __restrict__ H,
                                                 const int* __restrict__ dg,
                                                 const int* __restrict__ col,
                                                 float* __restrict__ out) {
    __shared__ int nbr[4][MAX_DEG];
    __shared__ int uniq[4][MAX_DEG];
    __shared__ int wcnt[4];
    const int wave = threadIdx.x >> 6;
    const int lane = threadIdx.x & 63;
    const int v    = blockIdx.x * 4 + wave;
    int d = dg[v];
    if (d > MAX_DEG) d = MAX_DEG;

    if (lane == 0) wcnt[wave] = 0;
    int id0 = -1, id1 = -1;
    if (lane < d)      { id0 = col[v * STRIDE + lane];      nbr[wave][lane]      = id0; }
    if (64 + lane < d) { id1 = col[v * STRIDE + 64 + lane]; nbr[wave][64 + lane] = id1; }
    __builtin_amdgcn_wave_barrier();   // wave-synchronous; pin scheduling across LDS use

    // keep entry i iff no j<i equals it (no early exit -> LDS reads pipeline)
    bool k0 = (lane < d);
    const int lim0 = k0 ? lane : 0;
    for (int j = 0; j < lim0; ++j) k0 = k0 & (nbr[wave][j] != id0);
    bool k1 = (64 + lane < d);
    const int lim1 = k1 ? (64 + lane) : 0;
    for (int j = 0; j < lim1; ++j) k1 = k1 & (nbr[wave][j] != id1);
    if (k0) uniq[wave][atomicAdd(&wcnt[wave], 1)] = id0;
    if (k1) uniq[wave][atomicAdd(&wcnt[wave], 1)] = id1;
    __builtin_amdgcn_wave_barrier();
    const int n  = wcnt[wave];
    const int f0 = lane * 8;              // lane covers 8 feats (uint4 = 8 bf16)

    float a0=0,a1=0,a2=0,a3=0,a4=0,a5=0,a6=0,a7=0;
    int e = 0;
    for (; e + 4 <= n; e += 4) {          // 4 rows in flight per iteration
        const int i0 = uniq[wave][e], i1 = uniq[wave][e+1],
                  i2 = uniq[wave][e+2], i3 = uniq[wave][e+3];
        uint4 h0 = *(const uint4*)&H[(size_t)i0 * OUT_F + f0];
        uint4 h1 = *(const uint4*)&H[(size_t)i1 * OUT_F + f0];
        uint4 h2 = *(const uint4*)&H[(size_t)i2 * OUT_F + f0];
        uint4 h3 = *(const uint4*)&H[(size_t)i3 * OUT_F + f0];
        a0 += bflo(h0.x)+bflo(h1.x)+bflo(h2.x)+bflo(h3.x);
        a1 += bfhi(h0.x)+bfhi(h1.x)+bfhi(h2.x)+bfhi(h3.x);
        a2 += bflo(h0.y)+bflo(h1.y)+bflo(h2.y)+bflo(h3.y);
        a3 += bfhi(h0.y)+bfhi(h1.y)+bfhi(h2.y)+bfhi(h3.y);
        a4 += bflo(h0.z)+bflo(h1.z)+bflo(h2.z)+bflo(h3.z);
        a5 += bfhi(h0.z)+bfhi(h1.z)+bfhi(h2.z)+bfhi(h3.z);
        a6 += bflo(h0.w)+bflo(h1.w)+bflo(h2.w)+bflo(h3.w);
        a7 += bfhi(h0.w)+bfhi(h1.w)+bfhi(h2.w)+bfhi(h3.w);
    }
    for (; e < n; ++e) {
        uint4 h0 = *(const uint4*)&H[(size_t)uniq[wave][e] * OUT_F + f0];
        a0 += bflo(h0.x); a1 += bfhi(h0.x);
        a2 += bflo(h0.y); a3 += bfhi(h0.y);
        a4 += bflo(h0.z); a5 += bfhi(h0.z);
        a6 += bflo(h0.w); a7 += bfhi(h0.w);
    }
    f32x4 o0 = {fmaxf(a0,0.f), fmaxf(a1,0.f), fmaxf(a2,0.f), fmaxf(a3,0.f)};
    f32x4 o1 = {fmaxf(a4,0.f), fmaxf(a5,0.f), fmaxf(a6,0.f), fmaxf(a7,0.f)};
    // out is never re-read -> nontemporal, keep L2 for the H gather table
    __builtin_nontemporal_store(o0, (f32x4*)&out[(size_t)v * OUT_F + f0]);
    __builtin_nontemporal_store(o1, (f32x4*)&out[(size_t)v * OUT_F + f0 + 4]);
}

extern "C" void kernel_launch(void* const* d_in, const int* in_sizes, int n_in,
                              void* d_out, int out_size, void* d_ws, size_t ws_size,
                              hipStream_t stream) {
    const float* x  = (const float*)d_in[0];
    const float* W  = (const float*)d_in[1];
    const float* b  = (const float*)d_in[2];
    const int*   ei = (const int*)d_in[3];      // [2, N_EDGES]: src then dst
    float* out = (float*)d_out;

    char* ws = (char*)d_ws;
    unsigned short* H   = (unsigned short*)(ws + HID_OFF);
    unsigned short* Wb  = (unsigned short*)(ws + WB_OFF);
    int*            deg = (int*)(ws + DEG_OFF);
    int*            col = (int*)(ws + COL_OFF);

    // 1) W -> bf16 (1 MB) + zero deg  (~1.5 us)
    prep<<<NW8 / 256, 256, 0, stream>>>(W, Wb, deg);

    // 2) GEMM w/ inline X fp32->bf16 staging (1024 blocks) + edge scatter (1024)
    gemm_scatter<<<2048, 256, 0, stream>>>(x, Wb, b, H, ei, ei + N_EDGES, deg, col);

    // 3) per-node dedup + gather + ReLU, one wave per node
    aggregate<<<N_NODES / 4, 256, 0, stream>>>(H, deg, col, out);
}